// Round 1
// baseline (2668.006 us; speedup 1.0000x reference)
//
#include <hip/hip_runtime.h>

#define NN 100000
#define HH 64
#define AN 92
#define NSTEP 8

__device__ __forceinline__ float sigf(float x) { return 1.0f / (1.0f + __expf(-x)); }
// tanh(x) = 1 - 2/(1+e^{2x}); saturates correctly at +/-inf, no NaN.
__device__ __forceinline__ float tanhfast(float x) { return 1.0f - 2.0f / (1.0f + __expf(2.0f * x)); }

// h[n][j] = b[j] + sum_k x[n][k] * W[k][j]   (one wave per node, lane = j)
__global__ __launch_bounds__(256) void k_reduce(const float* __restrict__ x,
                                                const float* __restrict__ W,
                                                const float* __restrict__ b,
                                                float* __restrict__ h) {
    int gid = blockIdx.x * 256 + threadIdx.x;
    int n = gid >> 6, j = gid & 63;
    if (n >= NN) return;
    const float* xr = x + (size_t)n * AN;   // wave-uniform row -> scalar-ish loads
    float acc = b[j];
#pragma unroll
    for (int k = 0; k < AN; ++k) acc = fmaf(xr[k], W[k * HH + j], acc);
    h[(size_t)n * HH + j] = acc;
}

// Wc[t][k][r] = sum_q W_g[t][k][q] * w_ih[r][q]    ([8][64][192])
__global__ __launch_bounds__(256) void k_wc(const float* __restrict__ Wg,
                                            const float* __restrict__ w_ih,
                                            float* __restrict__ Wc) {
    __shared__ float wl[192 * 65];   // padded: bank = (r + q) % 32, conflict-free
    for (int i = threadIdx.x; i < 192 * 64; i += 256) {
        int r = i >> 6, q = i & 63;
        wl[r * 65 + q] = w_ih[i];
    }
    __syncthreads();
    int gid = blockIdx.x * 256 + threadIdx.x;
    if (gid >= NSTEP * 64 * 192) return;
    int r = gid % 192;
    int k = (gid / 192) & 63;
    int t = gid / (192 * 64);
    const float* wg = Wg + t * 4096 + k * 64;   // wave-uniform (64-range never crosses a 192 group)
    float acc = 0.f;
#pragma unroll
    for (int q = 0; q < 64; ++q) acc = fmaf(wg[q], wl[r * 65 + q], acc);
    Wc[gid] = acc;
}

// S[dst[e]][c] += h[src[e]][c]   (one wave per edge, lane = c)
__global__ __launch_bounds__(256) void k_scatter(const float* __restrict__ h,
                                                 const int* __restrict__ src,
                                                 const int* __restrict__ dst,
                                                 float* __restrict__ S, int E) {
    int gid = blockIdx.x * 256 + threadIdx.x;
    int e = gid >> 6, c = gid & 63;
    if (e >= E) return;
    int sn = src[e], dn = dst[e];   // wave-uniform
    atomicAdd(S + (size_t)dn * HH + c, h[(size_t)sn * HH + c]);
}

// GRU cell, in place on h. gi = S @ Wc_t + b_ih ; gh = h @ w_hh^T + b_hh.
// 4 nodes per wave; both weight matrices staged in LDS with stride-193 padding.
__global__ __launch_bounds__(1024) void k_gru(const float* __restrict__ S,
                                              float* __restrict__ h,
                                              const float* __restrict__ Wc_t,
                                              const float* __restrict__ w_hh,
                                              const float* __restrict__ b_ih,
                                              const float* __restrict__ b_hh) {
    __shared__ float wi[64 * 193];   // wi[k*193 + r] = Wc_t[k][r]
    __shared__ float wh[64 * 193];   // wh[k*193 + r] = w_hh[r][k]
    for (int i = threadIdx.x; i < 64 * 192; i += 1024) {
        int k = i / 192, r = i % 192;
        wi[k * 193 + r] = Wc_t[i];
    }
    for (int i = threadIdx.x; i < 192 * 64; i += 1024) {
        int r = i >> 6, k = i & 63;
        wh[k * 193 + r] = w_hh[i];
    }
    __syncthreads();
    int lane = threadIdx.x & 63;
    int wave = threadIdx.x >> 6;   // 0..15
    float bri = b_ih[lane], bzi = b_ih[64 + lane], bni = b_ih[128 + lane];
    float brh = b_hh[lane], bzh = b_hh[64 + lane], bnh = b_hh[128 + lane];

    for (int n0 = (blockIdx.x * 16 + wave) * 4; n0 < NN; n0 += gridDim.x * 64) {
        float cr[4], cz[4], ci[4], ch[4];
#pragma unroll
        for (int u = 0; u < 4; ++u) {
            cr[u] = bri + brh; cz[u] = bzi + bzh; ci[u] = bni; ch[u] = bnh;
        }
        for (int k4 = 0; k4 < 64; k4 += 4) {
            float ab[4][4], hb[4][4];
#pragma unroll
            for (int u = 0; u < 4; ++u) {
                float4 av = *(const float4*)(S + (size_t)(n0 + u) * HH + k4);
                float4 hv = *(const float4*)(h + (size_t)(n0 + u) * HH + k4);
                ab[u][0] = av.x; ab[u][1] = av.y; ab[u][2] = av.z; ab[u][3] = av.w;
                hb[u][0] = hv.x; hb[u][1] = hv.y; hb[u][2] = hv.z; hb[u][3] = hv.w;
            }
#pragma unroll
            for (int kk = 0; kk < 4; ++kk) {
                int k = k4 + kk;
                float wri = wi[k * 193 + lane];
                float wzi = wi[k * 193 + 64 + lane];
                float wni = wi[k * 193 + 128 + lane];
                float wrh = wh[k * 193 + lane];
                float wzh = wh[k * 193 + 64 + lane];
                float wnh = wh[k * 193 + 128 + lane];
#pragma unroll
                for (int u = 0; u < 4; ++u) {
                    cr[u] = fmaf(ab[u][kk], wri, cr[u]);
                    cr[u] = fmaf(hb[u][kk], wrh, cr[u]);
                    cz[u] = fmaf(ab[u][kk], wzi, cz[u]);
                    cz[u] = fmaf(hb[u][kk], wzh, cz[u]);
                    ci[u] = fmaf(ab[u][kk], wni, ci[u]);
                    ch[u] = fmaf(hb[u][kk], wnh, ch[u]);
                }
            }
        }
#pragma unroll
        for (int u = 0; u < 4; ++u) {
            float r = sigf(cr[u]);
            float z = sigf(cz[u]);
            float nn2 = tanhfast(fmaf(r, ch[u], ci[u]));
            float hold = h[(size_t)(n0 + u) * HH + lane];
            h[(size_t)(n0 + u) * HH + lane] = (1.f - z) * nn2 + z * hold;
        }
    }
}

// out[i] = sigmoid(dot(h[idx[i]], W_lin) + b_lin)   (one wave per output row)
__global__ __launch_bounds__(256) void k_readout(const float* __restrict__ h,
                                                 const int* __restrict__ idx,
                                                 const float* __restrict__ Wl,
                                                 const float* __restrict__ bl,
                                                 float* __restrict__ out, int B) {
    int gid = blockIdx.x * 256 + threadIdx.x;
    int i = gid >> 6, lane = gid & 63;
    if (i >= B) return;
    int n = idx[i];   // wave-uniform
    float v = h[(size_t)n * HH + lane] * Wl[lane];
#pragma unroll
    for (int off = 32; off > 0; off >>= 1) v += __shfl_xor(v, off, 64);
    if (lane == 0) out[i] = sigf(v + bl[0]);
}

extern "C" void kernel_launch(void* const* d_in, const int* in_sizes, int n_in,
                              void* d_out, int out_size, void* d_ws, size_t ws_size,
                              hipStream_t stream) {
    const float* x     = (const float*)d_in[0];
    const int*   ei    = (const int*)d_in[1];   // [2, E]: src row then dst row
    const int*   idx   = (const int*)d_in[2];
    const float* W_red = (const float*)d_in[3];
    const float* b_red = (const float*)d_in[4];
    const float* W_g   = (const float*)d_in[5];
    const float* w_ih  = (const float*)d_in[6];
    const float* w_hh  = (const float*)d_in[7];
    const float* b_ih  = (const float*)d_in[8];
    const float* b_hh  = (const float*)d_in[9];
    const float* W_lin = (const float*)d_in[10];
    const float* b_lin = (const float*)d_in[11];
    float* out = (float*)d_out;
    const int E = in_sizes[1] / 2;
    const int B = in_sizes[2];

    float* h  = (float*)d_ws;                 // [NN,64]  25.6 MB
    float* S  = h + (size_t)NN * HH;          // [NN,64]  25.6 MB
    float* Wc = S + (size_t)NN * HH;          // [8,64,192] 393 KB

    k_reduce<<<(NN * 64 + 255) / 256, 256, 0, stream>>>(x, W_red, b_red, h);
    k_wc<<<(NSTEP * 64 * 192 + 255) / 256, 256, 0, stream>>>(W_g, w_ih, Wc);

    for (int t = 0; t < NSTEP; ++t) {
        hipMemsetAsync(S, 0, (size_t)NN * HH * sizeof(float), stream);
        k_scatter<<<(E * 64 + 255) / 256, 256, 0, stream>>>(h, ei, ei + E, S, E);
        k_gru<<<256, 1024, 0, stream>>>(S, h, Wc + (size_t)t * 64 * 192, w_hh, b_ih, b_hh);
    }

    k_readout<<<(B * 64 + 255) / 256, 256, 0, stream>>>(h, idx, W_lin, b_lin, out, B);
}

// Round 2
// 2022.059 us; speedup vs baseline: 1.3195x; 1.3195x over previous
//
#include <hip/hip_runtime.h>

#define NN 100000
#define HH 64
#define AN 92
#define NSTEP 8

__device__ __forceinline__ float sigf(float x) { return 1.0f / (1.0f + __expf(-x)); }
// tanh(x) = 1 - 2/(1+e^{2x}); saturates correctly, no NaN.
__device__ __forceinline__ float tanhfast(float x) { return 1.0f - 2.0f / (1.0f + __expf(2.0f * x)); }

// h[n][j] = b[j] + sum_k x[n][k] * W[k][j]   (one wave per node, lane = j)
__global__ __launch_bounds__(256) void k_reduce(const float* __restrict__ x,
                                                const float* __restrict__ W,
                                                const float* __restrict__ b,
                                                float* __restrict__ h) {
    int gid = blockIdx.x * 256 + threadIdx.x;
    int n = gid >> 6, j = gid & 63;
    if (n >= NN) return;
    const float* xr = x + (size_t)n * AN;
    float acc = b[j];
#pragma unroll
    for (int k = 0; k < AN; ++k) acc = fmaf(xr[k], W[k * HH + j], acc);
    h[(size_t)n * HH + j] = acc;
}

// Wc[t][k][r] = sum_q W_g[t][k][q] * w_ih[r][q]    ([8][64][192])
__global__ __launch_bounds__(256) void k_wc(const float* __restrict__ Wg,
                                            const float* __restrict__ w_ih,
                                            float* __restrict__ Wc) {
    __shared__ float wl[192 * 65];
    for (int i = threadIdx.x; i < 192 * 64; i += 256) {
        int r = i >> 6, q = i & 63;
        wl[r * 65 + q] = w_ih[i];
    }
    __syncthreads();
    int gid = blockIdx.x * 256 + threadIdx.x;
    if (gid >= NSTEP * 64 * 192) return;
    int r = gid % 192;
    int k = (gid / 192) & 63;
    int t = gid / (192 * 64);
    const float* wg = Wg + t * 4096 + k * 64;
    float acc = 0.f;
#pragma unroll
    for (int q = 0; q < 64; ++q) acc = fmaf(wg[q], wl[r * 65 + q], acc);
    Wc[gid] = acc;
}

// cur[dst[e]]++  (histogram of in-degrees)
__global__ __launch_bounds__(256) void k_hist(const int* __restrict__ dst, int* __restrict__ cur, int E) {
    int e = blockIdx.x * 256 + threadIdx.x;
    if (e >= E) return;
    atomicAdd(cur + dst[e], 1);
}

// In-place exclusive prefix sum over cur[0..NN). Single block, two-level.
__global__ __launch_bounds__(1024) void k_scan(int* __restrict__ cur) {
    __shared__ int ps[1024];
    const int CH = (NN + 1023) / 1024;   // 98
    int t = threadIdx.x;
    int lo = t * CH, hi = min(lo + CH, NN);
    int s = 0;
    for (int i = lo; i < hi; ++i) s += cur[i];
    ps[t] = s;
    __syncthreads();
    for (int off = 1; off < 1024; off <<= 1) {
        int v = (t >= off) ? ps[t - off] : 0;
        __syncthreads();
        ps[t] += v;
        __syncthreads();
    }
    int run = (t == 0) ? 0 : ps[t - 1];   // exclusive prefix of this chunk
    for (int i = lo; i < hi; ++i) {
        int c = cur[i];
        cur[i] = run;
        run += c;
    }
}

// srt[cur[dst[e]]++] = src[e]   (after this, cur[n] = end offset of segment n)
__global__ __launch_bounds__(256) void k_place(const int* __restrict__ src,
                                               const int* __restrict__ dst,
                                               int* __restrict__ cur,
                                               int* __restrict__ srt, int E) {
    int e = blockIdx.x * 256 + threadIdx.x;
    if (e >= E) return;
    int pos = atomicAdd(cur + dst[e], 1);
    srt[pos] = src[e];
}

// Fused CSR aggregate + GRU. One wave per 4 nodes, lane = channel.
// seg(n) = [n ? cur[n-1] : 0, cur[n]).  h_new = GRU(aggr, h_old).
__global__ __launch_bounds__(1024) void k_step(const float* __restrict__ h_old,
                                               float* __restrict__ h_new,
                                               const int* __restrict__ cur,
                                               const int* __restrict__ srt,
                                               const float* __restrict__ Wc_t,
                                               const float* __restrict__ w_hh,
                                               const float* __restrict__ b_ih,
                                               const float* __restrict__ b_hh) {
    __shared__ float wi[64 * 193];        // wi[k*193 + r] = Wc_t[k][r]
    __shared__ float wh[64 * 193];        // wh[k*193 + r] = w_hh[r][k]
    __shared__ float stage[16][8][68];    // per-wave: 4 acc rows + 4 h rows
    for (int i = threadIdx.x; i < 64 * 192; i += 1024) {
        int k = i / 192, r = i % 192;
        wi[k * 193 + r] = Wc_t[i];
    }
    for (int i = threadIdx.x; i < 192 * 64; i += 1024) {
        int r = i >> 6, k = i & 63;
        wh[k * 193 + r] = w_hh[i];
    }
    __syncthreads();
    int lane = threadIdx.x & 63;
    int wave = threadIdx.x >> 6;   // 0..15
    float bri = b_ih[lane], bzi = b_ih[64 + lane], bni = b_ih[128 + lane];
    float brh = b_hh[lane], bzh = b_hh[64 + lane], bnh = b_hh[128 + lane];

    for (int n0 = (blockIdx.x * 16 + wave) * 4; n0 < NN; n0 += gridDim.x * 64) {
        float hr[4];
        // ---- Phase A: CSR gather-sum into registers, stage to per-wave LDS ----
#pragma unroll
        for (int u = 0; u < 4; ++u) {
            int n = n0 + u;                          // NN % 4 == 0, no tail
            int st = (n == 0) ? 0 : cur[n - 1];
            int en = cur[n];
            float a = 0.f;
            for (int j = st; j < en; ++j)
                a += h_old[(size_t)srt[j] * HH + lane];   // coalesced 256B row
            hr[u] = h_old[(size_t)n * HH + lane];
            stage[wave][u][lane] = a;
            stage[wave][4 + u][lane] = hr[u];
        }
        // stage is per-wave: no barrier needed (compiler inserts lgkmcnt waits)
        // ---- Phase B: GRU matvecs via LDS broadcasts ----
        float cr[4], cz[4], ci[4], ch[4];
#pragma unroll
        for (int u = 0; u < 4; ++u) {
            cr[u] = bri + brh; cz[u] = bzi + bzh; ci[u] = bni; ch[u] = bnh;
        }
        for (int k4 = 0; k4 < 64; k4 += 4) {
            float ab[4][4], hb[4][4];
#pragma unroll
            for (int u = 0; u < 4; ++u) {
                float4 av = *(const float4*)&stage[wave][u][k4];
                float4 hv = *(const float4*)&stage[wave][4 + u][k4];
                ab[u][0] = av.x; ab[u][1] = av.y; ab[u][2] = av.z; ab[u][3] = av.w;
                hb[u][0] = hv.x; hb[u][1] = hv.y; hb[u][2] = hv.z; hb[u][3] = hv.w;
            }
#pragma unroll
            for (int kk = 0; kk < 4; ++kk) {
                int k = k4 + kk;
                float wri = wi[k * 193 + lane];
                float wzi = wi[k * 193 + 64 + lane];
                float wni = wi[k * 193 + 128 + lane];
                float wrh = wh[k * 193 + lane];
                float wzh = wh[k * 193 + 64 + lane];
                float wnh = wh[k * 193 + 128 + lane];
#pragma unroll
                for (int u = 0; u < 4; ++u) {
                    cr[u] = fmaf(ab[u][kk], wri, cr[u]);
                    cr[u] = fmaf(hb[u][kk], wrh, cr[u]);
                    cz[u] = fmaf(ab[u][kk], wzi, cz[u]);
                    cz[u] = fmaf(hb[u][kk], wzh, cz[u]);
                    ci[u] = fmaf(ab[u][kk], wni, ci[u]);
                    ch[u] = fmaf(hb[u][kk], wnh, ch[u]);
                }
            }
        }
#pragma unroll
        for (int u = 0; u < 4; ++u) {
            float r = sigf(cr[u]);
            float z = sigf(cz[u]);
            float nn2 = tanhfast(fmaf(r, ch[u], ci[u]));
            h_new[(size_t)(n0 + u) * HH + lane] = (1.f - z) * nn2 + z * hr[u];
        }
    }
}

// out[i] = sigmoid(dot(h[idx[i]], W_lin) + b_lin)
__global__ __launch_bounds__(256) void k_readout(const float* __restrict__ h,
                                                 const int* __restrict__ idx,
                                                 const float* __restrict__ Wl,
                                                 const float* __restrict__ bl,
                                                 float* __restrict__ out, int B) {
    int gid = blockIdx.x * 256 + threadIdx.x;
    int i = gid >> 6, lane = gid & 63;
    if (i >= B) return;
    int n = idx[i];
    float v = h[(size_t)n * HH + lane] * Wl[lane];
#pragma unroll
    for (int off = 32; off > 0; off >>= 1) v += __shfl_xor(v, off, 64);
    if (lane == 0) out[i] = sigf(v + bl[0]);
}

extern "C" void kernel_launch(void* const* d_in, const int* in_sizes, int n_in,
                              void* d_out, int out_size, void* d_ws, size_t ws_size,
                              hipStream_t stream) {
    const float* x     = (const float*)d_in[0];
    const int*   ei    = (const int*)d_in[1];   // [2, E]: src row then dst row
    const int*   idx   = (const int*)d_in[2];
    const float* W_red = (const float*)d_in[3];
    const float* b_red = (const float*)d_in[4];
    const float* W_g   = (const float*)d_in[5];
    const float* w_ih  = (const float*)d_in[6];
    const float* w_hh  = (const float*)d_in[7];
    const float* b_ih  = (const float*)d_in[8];
    const float* b_hh  = (const float*)d_in[9];
    const float* W_lin = (const float*)d_in[10];
    const float* b_lin = (const float*)d_in[11];
    float* out = (float*)d_out;
    const int E = in_sizes[1] / 2;
    const int B = in_sizes[2];
    const int* src = ei;
    const int* dst = ei + E;

    float* hA = (float*)d_ws;                         // [NN,64] 25.6 MB
    float* hB = hA + (size_t)NN * HH;                 // [NN,64] 25.6 MB
    float* Wc = hB + (size_t)NN * HH;                 // [8,64,192] 393 KB
    int*   cur = (int*)(Wc + (size_t)NSTEP * HH * 3 * HH);  // [NN] 400 KB
    int*   srt = cur + NN;                            // [E] 3.2 MB

    // ---- CSR build (counting sort by dst) ----
    hipMemsetAsync(cur, 0, NN * sizeof(int), stream);
    k_hist<<<(E + 255) / 256, 256, 0, stream>>>(dst, cur, E);
    k_scan<<<1, 1024, 0, stream>>>(cur);
    k_place<<<(E + 255) / 256, 256, 0, stream>>>(src, dst, cur, srt, E);

    // ---- node init + folded weights ----
    k_reduce<<<(NN * 64 + 255) / 256, 256, 0, stream>>>(x, W_red, b_red, hA);
    k_wc<<<(NSTEP * 64 * 192 + 255) / 256, 256, 0, stream>>>(W_g, w_ih, Wc);

    // ---- 8 propagation steps, ping-pong hA/hB ----
    for (int t = 0; t < NSTEP; ++t) {
        const float* hin = (t & 1) ? hB : hA;
        float*       hout = (t & 1) ? hA : hB;
        k_step<<<256, 1024, 0, stream>>>(hin, hout, cur, srt,
                                         Wc + (size_t)t * HH * 3 * HH, w_hh, b_ih, b_hh);
    }
    // after 8 steps result is back in hA

    k_readout<<<(B * 64 + 255) / 256, 256, 0, stream>>>(hA, idx, W_lin, b_lin, out, B);
}